// Round 9
// baseline (141.779 us; speedup 1.0000x reference)
//
#include <hip/hip_runtime.h>
#include <hip/hip_bf16.h>
#include <math.h>

#define NPIX 65536
#define HEPS (6.4f / 255.0f)
#define LN2_50 34.65735902799726f   // 50 * ln(2): folds log2->ln and 1/sigma

typedef __bf16 bf16x8 __attribute__((ext_vector_type(8)));
typedef float  f32x4  __attribute__((ext_vector_type(4)));

#define ROWS 72                 // bf16 elems per matrix row (64 px + 8 pad -> 144B)
#define MATS (64 * ROWS)        // elems per 64x64 matrix

__device__ __forceinline__ float clamp01(float x) { return fminf(fmaxf(x, 0.f), 1.f); }

// Channel-fused histogram. grid: 8*SEG blocks, 384 threads (6 waves = 3ch x 2 pxhalf).
// Per 64-px chunk:
//  E phase: 384 items (rcp-row, bin, pxhalf) -> 3 rcp-rows evaluated ONCE, stored as
//           6 bf16 matrices in LDS [bin][px] (weighted W01,W02r; plain K02,K12,K12r;
//           reversed copies implement k(-d-delta_u) = k(d-delta_{63-u})).
//  M phase: wave (ch,pxh) runs the verified 4x4-tile MFMA structure; A/B fragments are
//           single ds_read_b128 row reads. Row stride 144B => 8-cyc-optimal LDS access.
// Epilogue: pxh pair-reduce via LDS (reusing kmat), partial stored fragment-permuted.
template <int SEG>
__global__ __launch_bounds__(384, 3) void hist_fused(const float* __restrict__ rgbd,
                                                     float* __restrict__ P,
                                                     float* __restrict__ ctrl) {
  constexpr int PPB = NPIX / SEG;   // pixels per block
  constexpr int NCH = PPB / 64;     // chunks per block
  const int blk = blockIdx.x;
  const int seg = blk & (SEG - 1);
  const int b   = blk / SEG;
  const int t = threadIdx.x;
  const int l = t & 63;
  const int w = t >> 6;             // wave 0..5
  const int ch  = w >> 1;           // channel for M phase
  const int pxh = w & 1;            // k-subtile half for M phase
  const int halfq = l & 15;
  const int grp   = l >> 4;

  if (blk == 0 && t < 16) ctrl[t] = 0.f;   // norms[8], acc, counter, pad

  __shared__ __align__(16) __bf16 kmat[6 * MATS];   // 55.3 KB
  __shared__ __align__(16) float dst[2][4][64];     // d01_50,d02_50,d12_50,iy (dbuf)

  const float* __restrict__ base = rgbd + (size_t)b * (4 * NPIX);
  const int pbase = seg * PPB;

  // eval item for this thread
  const int mrow = t >> 7;          // 0..2: which rcp-row (wave-pair-uniform)
  const int ebin = (t >> 1) & 63;
  const int eph  = t & 1;
  const float delta50 = (-3.f + (float)ebin * (6.f / 63.f)) * 50.f;

  f32x4 acc[16];
#pragma unroll
  for (int i = 0; i < 16; ++i) acc[i] = (f32x4){0.f, 0.f, 0.f, 0.f};

  // prologue: preproc chunk 0 (wave 5 owns preproc; lightest eval row)
  if (t >= 320) {
    const int p = pbase + l;
    const float pr = base[p], pg = base[NPIX + p], pb = base[2 * NPIX + p];
    const float r  = clamp01(fmaf(pr, 0.5f, 0.5f));
    const float g  = clamp01(fmaf(pg, 0.5f, 0.5f));
    const float bl = clamp01(fmaf(pb, 0.5f, 0.5f));
    const float iy = sqrtf(fmaf(r, r, fmaf(g, g, fmaf(bl, bl, HEPS))));
    const float a = __log2f(r + HEPS), bq = __log2f(g + HEPS), cq = __log2f(bl + HEPS);
    dst[0][0][l] = (a - bq) * LN2_50;
    dst[0][1][l] = (a - cq) * LN2_50;
    dst[0][2][l] = (bq - cq) * LN2_50;
    dst[0][3][l] = iy;
  }
  __syncthreads();

  for (int ck = 0; ck < NCH; ++ck) {
    const int cur = ck & 1;
    // issue next chunk's pixel loads early (wave 5)
    float pr = 0.f, pg = 0.f, pb = 0.f;
    const bool pre = (t >= 320) && (ck + 1 < NCH);
    if (pre) {
      const int p = pbase + (ck + 1) * 64 + l;
      pr = base[p]; pg = base[NPIX + p]; pb = base[2 * NPIX + p];
    }

    // ---- E phase: this thread's 32 px of one rcp-row/bin ----
    {
      const f32x4* __restrict__ dr = (const f32x4*)&dst[cur][mrow][eph * 32];
      const f32x4* __restrict__ ir = (const f32x4*)&dst[cur][3][eph * 32];
      const int pxo = eph * 32;
      __bf16* __restrict__ m0 = kmat + (size_t)(mrow * 2)     * MATS;  // W01 / K02 / K12
      __bf16* __restrict__ m1 = kmat + (size_t)(mrow * 2 + 1) * MATS;  // W01r / W02r / K12r
      const int rA = ebin * ROWS + pxo;
      const int rR = (63 - ebin) * ROWS + pxo;
#pragma unroll
      for (int g = 0; g < 4; ++g) {
        const f32x4 dA = dr[2 * g], dB = dr[2 * g + 1];
        const f32x4 xA = dA - delta50, xB = dB - delta50;
        float k[8];
#pragma unroll
        for (int e = 0; e < 4; ++e) {
          k[e]     = __builtin_amdgcn_rcpf(fmaf(xA[e], xA[e], 1.f));
          k[e + 4] = __builtin_amdgcn_rcpf(fmaf(xB[e], xB[e], 1.f));
        }
        if (mrow == 2) {                      // K12 & K12r: plain, same values
          bf16x8 pk;
#pragma unroll
          for (int e = 0; e < 8; ++e) pk[e] = (__bf16)k[e];
          *(bf16x8*)&m0[rA + g * 8] = pk;
          *(bf16x8*)&m1[rR + g * 8] = pk;
        } else {
          const f32x4 iA = ir[2 * g], iB = ir[2 * g + 1];
          bf16x8 wg;
#pragma unroll
          for (int e = 0; e < 4; ++e) {
            wg[e]     = (__bf16)(iA[e] * k[e]);
            wg[e + 4] = (__bf16)(iB[e] * k[e + 4]);
          }
          if (mrow == 0) {                    // W01 & W01r: weighted both
            *(bf16x8*)&m0[rA + g * 8] = wg;
            *(bf16x8*)&m1[rR + g * 8] = wg;
          } else {                            // K02 plain, W02r weighted
            bf16x8 pk;
#pragma unroll
            for (int e = 0; e < 8; ++e) pk[e] = (__bf16)k[e];
            *(bf16x8*)&m0[rA + g * 8] = pk;
            *(bf16x8*)&m1[rR + g * 8] = wg;
          }
        }
      }
    }

    // preproc next chunk into the other dst buffer (wave 5)
    if (pre) {
      const float r  = clamp01(fmaf(pr, 0.5f, 0.5f));
      const float g  = clamp01(fmaf(pg, 0.5f, 0.5f));
      const float bl = clamp01(fmaf(pb, 0.5f, 0.5f));
      const float iy = sqrtf(fmaf(r, r, fmaf(g, g, fmaf(bl, bl, HEPS))));
      const float a = __log2f(r + HEPS), bq = __log2f(g + HEPS), cq = __log2f(bl + HEPS);
      dst[cur ^ 1][0][l] = (a - bq) * LN2_50;
      dst[cur ^ 1][1][l] = (a - cq) * LN2_50;
      dst[cur ^ 1][2][l] = (bq - cq) * LN2_50;
      dst[cur ^ 1][3][l] = iy;
    }
    __syncthreads();   // kmat ready

    // ---- M phase: verified 4x4-tile MFMA, fragments = b128 row reads ----
    {
      const __bf16* __restrict__ Am;
      const __bf16* __restrict__ Bm;
      if (ch == 0)      { Am = kmat + 0 * MATS; Bm = kmat + 2 * MATS; }  // W01,  K02
      else if (ch == 1) { Am = kmat + 1 * MATS; Bm = kmat + 4 * MATS; }  // W01r, K12
      else              { Am = kmat + 3 * MATS; Bm = kmat + 5 * MATS; }  // W02r, K12r
      const int kpx = pxh * 32 + grp * 8;     // this lane's 8 px (k)
      bf16x8 bfv[4];
#pragma unroll
      for (int vt = 0; vt < 4; ++vt)
        bfv[vt] = *(const bf16x8*)&Bm[(vt * 16 + halfq) * ROWS + kpx];
#pragma unroll
      for (int ut = 0; ut < 4; ++ut) {
        const bf16x8 af = *(const bf16x8*)&Am[(ut * 16 + halfq) * ROWS + kpx];
#pragma unroll
        for (int vt = 0; vt < 4; ++vt)
          acc[ut * 4 + vt] =
              __builtin_amdgcn_mfma_f32_16x16x32_bf16(af, bfv[vt], acc[ut * 4 + vt], 0, 0, 0);
      }
    }
    __syncthreads();   // kmat consumable for next E
  }

  // ---- epilogue: add pxh pairs (reuse kmat as f32x4 slab[3][16][64]) ----
  f32x4* __restrict__ slab = (f32x4*)kmat;
  if (pxh == 1) {
#pragma unroll
    for (int i = 0; i < 16; ++i) slab[(ch * 16 + i) * 64 + l] = acc[i];
  }
  __syncthreads();
  if (pxh == 0) {
    f32x4* __restrict__ Pv = (f32x4*)(P + ((size_t)blk * 3 + ch) * 4096);
#pragma unroll
    for (int i = 0; i < 16; ++i) Pv[i * 64 + l] = acc[i] + slab[(ch * 16 + i) * 64 + l];
  }
}

// ---- stage 2: sum SEG partials per (b,ch,bin); in-place into seg-0 slice ----
template <int SEG>
__global__ __launch_bounds__(256) void reduce_partials(float* __restrict__ P,
                                                       float* __restrict__ norms) {
  const int e  = blockIdx.x * 256 + threadIdx.x;   // 0..98303
  const int bc = e >> 12;                          // (b,ch) 0..23
  const int si = e & 4095;
  const int b  = bc / 3;
  const int c  = bc - 3 * b;
  float* __restrict__ p0 = P + ((size_t)b * SEG * 3 + c) * 4096 + si;
  float s = 0.f;
#pragma unroll
  for (int sg = 0; sg < SEG; ++sg) s += p0[(size_t)sg * 3 * 4096];
  p0[0] = s;

  __shared__ float red[4];
  float ns = s;
#pragma unroll
  for (int off = 32; off > 0; off >>= 1) ns += __shfl_down(ns, off);
  if ((threadIdx.x & 63) == 0) red[threadIdx.x >> 6] = ns;
  __syncthreads();
  if (threadIdx.x == 0)
    atomicAdd(&norms[b], red[0] + red[1] + red[2] + red[3]);
}

// ---- stage 3: Hellinger loss + fused final (last block writes out) ----
template <int SEG>
__global__ __launch_bounds__(256) void loss_final(const float* __restrict__ P,
                                                  const float* __restrict__ norms,
                                                  const float* __restrict__ th,
                                                  float* __restrict__ acc,
                                                  unsigned* __restrict__ counter,
                                                  float* __restrict__ out) {
  float s = 0.f;
  for (int idx = blockIdx.x * 256 + threadIdx.x; idx < 8 * 12288;
       idx += gridDim.x * 256) {
    const int b  = idx / 12288;
    const int r  = idx - b * 12288;
    const int c  = r >> 12;
    const int si = r & 4095;                 // fragment-permuted storage index
    const int rg = si & 3;
    const int q  = si >> 2;
    const int l  = q & 63;
    const int i  = q >> 6;
    const int row = (i >> 2) * 16 + (l >> 4) * 4 + rg;
    const int col = (i & 3) * 16 + (l & 15);
    const float h = P[((size_t)b * SEG * 3 + c) * 4096 + si] / (norms[b] + HEPS);
    const float d = sqrtf(th[c * 4096 + row * 64 + col]) - sqrtf(h);
    s += d * d;
  }
  __shared__ float red[4];
#pragma unroll
  for (int off = 32; off > 0; off >>= 1) s += __shfl_down(s, off);
  if ((threadIdx.x & 63) == 0) red[threadIdx.x >> 6] = s;
  __syncthreads();
  if (threadIdx.x == 0) {
    atomicAdd(acc, red[0] + red[1] + red[2] + red[3]);
    __threadfence();
    const unsigned old = atomicAdd(counter, 1u);
    if (old == (unsigned)(gridDim.x - 1)) {
      const float tot = atomicAdd(acc, 0.f);
      out[0] = sqrtf(tot) * 0.08838834764831845f;   // (1/sqrt(2))/B, B=8
    }
  }
}

template <int SEG>
static void run_path(const float* rgbd, const float* th, float* out,
                     void* d_ws, hipStream_t stream) {
  const size_t nP = (size_t)8 * SEG * 3 * 4096;
  float*    P       = (float*)d_ws;
  float*    ctrl    = P + nP;
  float*    norms   = ctrl;
  float*    acc     = ctrl + 8;
  unsigned* counter = (unsigned*)(ctrl + 9);

  hist_fused<SEG><<<8 * SEG, 384, 0, stream>>>(rgbd, P, ctrl);
  reduce_partials<SEG><<<384, 256, 0, stream>>>(P, norms);
  loss_final<SEG><<<96, 256, 0, stream>>>(P, norms, th, acc, counter, out);
}

extern "C" void kernel_launch(void* const* d_in, const int* in_sizes, int n_in,
                              void* d_out, int out_size, void* d_ws, size_t ws_size,
                              hipStream_t stream) {
  const float* rgbd = (const float*)d_in[0];   // [8,4,256,256]
  const float* th   = (const float*)d_in[1];   // [3,64,64]
  float* out = (float*)d_out;

  const size_t need64 = ((size_t)8 * 64 * 3 * 4096 + 64) * sizeof(float);  // 25.2 MB (fit confirmed r7)
  if (ws_size >= need64)
    run_path<64>(rgbd, th, out, d_ws, stream);
  else
    run_path<32>(rgbd, th, out, d_ws, stream);
}

// Round 10
// 131.957 us; speedup vs baseline: 1.0744x; 1.0744x over previous
//
#include <hip/hip_runtime.h>
#include <hip/hip_bf16.h>
#include <math.h>

#define NPIX 65536
#define HEPS (6.4f / 255.0f)
#define LN2_50 34.65735902799726f   // 50 * ln(2): folds log2->ln and 1/sigma

typedef __bf16 bf16x8 __attribute__((ext_vector_type(8)));
typedef float  f32x4  __attribute__((ext_vector_type(4)));

__device__ __forceinline__ float clamp01(float x) { return fminf(fmaxf(x, 0.f), 1.f); }

// XOR-swizzled elem offset within one 64x64 bf16 matrix (row stride 128B).
// T2-style: spreads rows across bank groups; b128 reads land 2-way (free).
__device__ __forceinline__ int swz(int row, int px) {
  return ((row << 6) + px) ^ ((row & 7) << 3);
}

// Channel-fused histogram, software-pipelined. grid: 8*SEG blocks, 384 thr (6 waves).
// Matrices per chunk (4, not 6 -- reversal is a read-time row flip):
//   W01 = Iy*k(d01), K02 = k(d02), W02 = Iy*k(d02), K12 = k(d12)
//   c0: A=W01[u],    B=K02[v];  c1: A=W01[63-u], B=K12[v];  c2: A=W02[63-u], B=K12[63-v]
// Pipeline per iter (ONE barrier): preproc(ck+2) by wave (ck+2)%6 | E(ck+1) | M(ck).
// kmat double-buffered by parity; pixel loads held in regs 6 chunks ahead.
template <int SEG>
__global__ __launch_bounds__(384, 3) void hist_fused(const float* __restrict__ rgbd,
                                                     float* __restrict__ P,
                                                     float* __restrict__ ctrl) {
  constexpr int PPB = NPIX / SEG;
  constexpr int NCH = PPB / 64;
  const int blk = blockIdx.x;
  const int seg = blk & (SEG - 1);
  const int b   = blk / SEG;
  const int t = threadIdx.x;
  const int l = t & 63;
  const int w = t >> 6;           // wave 0..5
  const int ch  = w >> 1;         // M-phase channel
  const int pxh = w & 1;          // M-phase k-half
  const int halfq = l & 15;
  const int grp   = l >> 4;

  if (blk == 0 && t < 16) ctrl[t] = 0.f;   // norms[8], acc, counter, pad

  __shared__ __align__(16) __bf16 kmat[2 * 4 * 4096];  // [buf][mat][row][px] 64 KB
  __shared__ float dst[2][4][64];                      // d01_50,d02_50,d12_50,iy

  const float* __restrict__ base = rgbd + (size_t)b * (4 * NPIX);
  const int pbase = seg * PPB;

  // eval item: (mrow, bin, eph) -- wave-uniform mrow (no divergence)
  const int ebin = (t >> 1) & 63;
  const int eph  = t & 1;
  const int mrow = t >> 7;        // 0:W01  1:K02+W02  2:K12
  const float delta50 = (-3.f + (float)ebin * (6.f / 63.f)) * 50.f;

  f32x4 acc[16];
#pragma unroll
  for (int i = 0; i < 16; ++i) acc[i] = (f32x4){0.f, 0.f, 0.f, 0.f};

  float pr = 0.f, pg = 0.f, pb = 0.f;   // prefetched pixel regs (one chunk/wave)

  auto loadpx = [&](int c) {
    const int p = pbase + c * 64 + l;
    pr = base[p]; pg = base[NPIX + p]; pb = base[2 * NPIX + p];
  };
  auto preproc = [&](int db) {
    const float r  = clamp01(fmaf(pr, 0.5f, 0.5f));
    const float g2 = clamp01(fmaf(pg, 0.5f, 0.5f));
    const float bl = clamp01(fmaf(pb, 0.5f, 0.5f));
    const float iy = sqrtf(fmaf(r, r, fmaf(g2, g2, fmaf(bl, bl, HEPS))));
    const float la = __log2f(r + HEPS);
    const float lg = __log2f(g2 + HEPS);
    const float lc = __log2f(bl + HEPS);
    dst[db][0][l] = (la - lg) * LN2_50;
    dst[db][1][l] = (la - lc) * LN2_50;
    dst[db][2][l] = (lg - lc) * LN2_50;
    dst[db][3][l] = iy;
  };
  auto evalph = [&](int cb) {
    const float* __restrict__ dr = &dst[cb][mrow][eph * 32];
    const float* __restrict__ ir = &dst[cb][3][eph * 32];
    __bf16* __restrict__ km = &kmat[cb * 4 * 4096];
    const int px0 = eph * 32;
#pragma unroll
    for (int g = 0; g < 4; ++g) {
      const f32x4 dA = *(const f32x4*)&dr[g * 8];
      const f32x4 dB = *(const f32x4*)&dr[g * 8 + 4];
      float kv[8];
#pragma unroll
      for (int e = 0; e < 4; ++e) {
        const float xA = dA[e] - delta50;
        const float xB = dB[e] - delta50;
        kv[e]     = __builtin_amdgcn_rcpf(fmaf(xA, xA, 1.f));
        kv[e + 4] = __builtin_amdgcn_rcpf(fmaf(xB, xB, 1.f));
      }
      const int so = swz(ebin, px0 + g * 8);
      if (mrow == 0) {
        const f32x4 iA = *(const f32x4*)&ir[g * 8];
        const f32x4 iB = *(const f32x4*)&ir[g * 8 + 4];
        bf16x8 wg;
#pragma unroll
        for (int e = 0; e < 4; ++e) {
          wg[e]     = (__bf16)(iA[e] * kv[e]);
          wg[e + 4] = (__bf16)(iB[e] * kv[e + 4]);
        }
        *(bf16x8*)&km[0 * 4096 + so] = wg;               // W01
      } else if (mrow == 1) {
        bf16x8 pk;
#pragma unroll
        for (int e = 0; e < 8; ++e) pk[e] = (__bf16)kv[e];
        *(bf16x8*)&km[1 * 4096 + so] = pk;               // K02
        const f32x4 iA = *(const f32x4*)&ir[g * 8];
        const f32x4 iB = *(const f32x4*)&ir[g * 8 + 4];
        bf16x8 wg;
#pragma unroll
        for (int e = 0; e < 4; ++e) {
          wg[e]     = (__bf16)(iA[e] * kv[e]);
          wg[e + 4] = (__bf16)(iB[e] * kv[e + 4]);
        }
        *(bf16x8*)&km[2 * 4096 + so] = wg;               // W02
      } else {
        bf16x8 pk;
#pragma unroll
        for (int e = 0; e < 8; ++e) pk[e] = (__bf16)kv[e];
        *(bf16x8*)&km[3 * 4096 + so] = pk;               // K12
      }
    }
  };
  auto mph = [&](int kb) {
    const __bf16* __restrict__ km = &kmat[kb * 4 * 4096];
    const int kpx = pxh * 32 + grp * 8;
    const __bf16* __restrict__ Am = (ch == 2) ? km + 2 * 4096 : km;        // W02 : W01
    const __bf16* __restrict__ Bm = (ch == 0) ? km + 1 * 4096 : km + 3 * 4096; // K02 : K12
    const int arev = (ch != 0);
    const int brev = (ch == 2);
    bf16x8 bfv[4];
#pragma unroll
    for (int vt = 0; vt < 4; ++vt) {
      int vr = vt * 16 + halfq;
      if (brev) vr = 63 - vr;
      bfv[vt] = *(const bf16x8*)&Bm[swz(vr, kpx)];
    }
#pragma unroll
    for (int ut = 0; ut < 4; ++ut) {
      int ur = ut * 16 + halfq;
      if (arev) ur = 63 - ur;
      const bf16x8 af = *(const bf16x8*)&Am[swz(ur, kpx)];
#pragma unroll
      for (int vt = 0; vt < 4; ++vt)
        acc[ut * 4 + vt] =
            __builtin_amdgcn_mfma_f32_16x16x32_bf16(af, bfv[vt], acc[ut * 4 + vt], 0, 0, 0);
    }
  };

  // ---- prologue: each wave loads chunk w; waves 0,1 preproc chunks 0,1 ----
  if (w < NCH) loadpx(w);
  if (w == 0) { preproc(0); if (6 < NCH) loadpx(6); }
  if (w == 1) { preproc(1); if (7 < NCH) loadpx(7); }
  __syncthreads();
  evalph(0);
  __syncthreads();

  // ---- main pipeline: ONE barrier per chunk ----
  for (int ck = 0; ck < NCH; ++ck) {
    const int cn = ck + 2;
    if (cn < NCH && w == (cn % 6)) {
      preproc(cn & 1);
      if (ck + 8 < NCH) loadpx(ck + 8);
    }
    if (ck + 1 < NCH) evalph((ck + 1) & 1);
    mph(ck & 1);
    __syncthreads();
  }

  // ---- epilogue: pxh-pair reduce via kmat-as-slab, fragment-permuted store ----
  f32x4* __restrict__ slab = (f32x4*)kmat;   // 3*16*64 f32x4 = 48 KB
  if (pxh == 1) {
#pragma unroll
    for (int i = 0; i < 16; ++i) slab[(ch * 16 + i) * 64 + l] = acc[i];
  }
  __syncthreads();
  if (pxh == 0) {
    f32x4* __restrict__ Pv = (f32x4*)(P + ((size_t)blk * 3 + ch) * 4096);
#pragma unroll
    for (int i = 0; i < 16; ++i) Pv[i * 64 + l] = acc[i] + slab[(ch * 16 + i) * 64 + l];
  }
}

// ---- stage 2: sum SEG partials per (b,ch,bin); in-place into seg-0 slice ----
template <int SEG>
__global__ __launch_bounds__(256) void reduce_partials(float* __restrict__ P,
                                                       float* __restrict__ norms) {
  const int e  = blockIdx.x * 256 + threadIdx.x;   // 0..98303
  const int bc = e >> 12;                          // (b,ch) 0..23
  const int si = e & 4095;
  const int b  = bc / 3;
  const int c  = bc - 3 * b;
  float* __restrict__ p0 = P + ((size_t)b * SEG * 3 + c) * 4096 + si;
  float s = 0.f;
#pragma unroll
  for (int sg = 0; sg < SEG; ++sg) s += p0[(size_t)sg * 3 * 4096];
  p0[0] = s;

  __shared__ float red[4];
  float ns = s;
#pragma unroll
  for (int off = 32; off > 0; off >>= 1) ns += __shfl_down(ns, off);
  if ((threadIdx.x & 63) == 0) red[threadIdx.x >> 6] = ns;
  __syncthreads();
  if (threadIdx.x == 0)
    atomicAdd(&norms[b], red[0] + red[1] + red[2] + red[3]);
}

// ---- stage 3: Hellinger loss + fused final (last block writes out) ----
template <int SEG>
__global__ __launch_bounds__(256) void loss_final(const float* __restrict__ P,
                                                  const float* __restrict__ norms,
                                                  const float* __restrict__ th,
                                                  float* __restrict__ acc,
                                                  unsigned* __restrict__ counter,
                                                  float* __restrict__ out) {
  float s = 0.f;
  for (int idx = blockIdx.x * 256 + threadIdx.x; idx < 8 * 12288;
       idx += gridDim.x * 256) {
    const int b  = idx / 12288;
    const int r  = idx - b * 12288;
    const int c  = r >> 12;
    const int si = r & 4095;                 // fragment-permuted storage index
    const int rg = si & 3;
    const int q  = si >> 2;
    const int l  = q & 63;
    const int i  = q >> 6;
    const int row = (i >> 2) * 16 + (l >> 4) * 4 + rg;
    const int col = (i & 3) * 16 + (l & 15);
    const float h = P[((size_t)b * SEG * 3 + c) * 4096 + si] / (norms[b] + HEPS);
    const float d = sqrtf(th[c * 4096 + row * 64 + col]) - sqrtf(h);
    s += d * d;
  }
  __shared__ float red[4];
#pragma unroll
  for (int off = 32; off > 0; off >>= 1) s += __shfl_down(s, off);
  if ((threadIdx.x & 63) == 0) red[threadIdx.x >> 6] = s;
  __syncthreads();
  if (threadIdx.x == 0) {
    atomicAdd(acc, red[0] + red[1] + red[2] + red[3]);
    __threadfence();
    const unsigned old = atomicAdd(counter, 1u);
    if (old == (unsigned)(gridDim.x - 1)) {
      const float tot = atomicAdd(acc, 0.f);
      out[0] = sqrtf(tot) * 0.08838834764831845f;   // (1/sqrt(2))/B, B=8
    }
  }
}

template <int SEG>
static void run_path(const float* rgbd, const float* th, float* out,
                     void* d_ws, hipStream_t stream) {
  const size_t nP = (size_t)8 * SEG * 3 * 4096;
  float*    P       = (float*)d_ws;
  float*    ctrl    = P + nP;
  float*    norms   = ctrl;
  float*    acc     = ctrl + 8;
  unsigned* counter = (unsigned*)(ctrl + 9);

  hist_fused<SEG><<<8 * SEG, 384, 0, stream>>>(rgbd, P, ctrl);
  reduce_partials<SEG><<<384, 256, 0, stream>>>(P, norms);
  loss_final<SEG><<<96, 256, 0, stream>>>(P, norms, th, acc, counter, out);
}

extern "C" void kernel_launch(void* const* d_in, const int* in_sizes, int n_in,
                              void* d_out, int out_size, void* d_ws, size_t ws_size,
                              hipStream_t stream) {
  const float* rgbd = (const float*)d_in[0];   // [8,4,256,256]
  const float* th   = (const float*)d_in[1];   // [3,64,64]
  float* out = (float*)d_out;

  const size_t need64 = ((size_t)8 * 64 * 3 * 4096 + 64) * sizeof(float);  // 25.2 MB (fit confirmed R7/R9)
  if (ws_size >= need64)
    run_path<64>(rgbd, th, out, d_ws, stream);
  else
    run_path<32>(rgbd, th, out, d_ws, stream);
}